// Round 1
// 502.938 us; speedup vs baseline: 1.0429x; 1.0429x over previous
//
#include <hip/hip_runtime.h>

typedef unsigned short u16;
typedef __attribute__((ext_vector_type(8))) _Float16 f16x8;
typedef __attribute__((ext_vector_type(4))) float f32x4;
typedef __attribute__((ext_vector_type(4))) int i32x4;
typedef __attribute__((ext_vector_type(4))) unsigned short us4;

__device__ __forceinline__ u16 f2h(float f) {
  _Float16 h = (_Float16)f;
  return __builtin_bit_cast(unsigned short, h);
}
__device__ __forceinline__ float sigm(float v) { return 1.0f / (1.0f + __expf(-v)); }
__device__ __forceinline__ float tanh_(float v) {
  float t = __expf(-2.0f * fabsf(v));
  float r = (1.0f - t) / (1.0f + t);
  return v >= 0.0f ? r : -r;
}

// async global->LDS DMA, 16 B per lane; LDS dest = wave-uniform base + lane*16
typedef const __attribute__((address_space(1))) unsigned int* gas_t;
typedef __attribute__((address_space(3))) unsigned int* las_t;
__device__ __forceinline__ void gl16(const u16* g, u16* l) {
  __builtin_amdgcn_global_load_lds((gas_t)g, (las_t)l, 16, 0, 0);
}

// ---------------------------------------------------------------------------
// prep_big:
//  blocks 0..2047   = [es 8][p 256]: scores[b][p] partial via float4 loads
//                     (16 outstanding 16B/lane), all-8-batch ILP shuffle
//                     reduce, ONE barrier, 8 atomics. Block 0 also -> sb.
//  blocks 2048..3071 = [set 2][chgrp 32][chunk 16] weight swizzle, LDS-free:
//                     18 float4 loads/thread, 9 coalesced 16B stores/thread
//                     directly in FRAGMENT-MAJOR layout:
//                       u16 idx within chunk = ((k9*4+gate)*64 + q*16+chrow)*8 + c8
//                     so conv4's A ds_read_b128 is linear lane*16 (0 conflicts).
// ---------------------------------------------------------------------------
__global__ __launch_bounds__(256, 2) void prep_big(
    const float* __restrict__ WQ, const float* __restrict__ WK,
    const float* __restrict__ txt, const float* __restrict__ WV,
    const float* __restrict__ Wsw, const float* __restrict__ Wsb,
    const float* __restrict__ wi, const float* __restrict__ wf,
    const float* __restrict__ wo, const float* __restrict__ wc,
    const float* __restrict__ ui, const float* __restrict__ uf,
    const float* __restrict__ uo, const float* __restrict__ uc,
    u16* __restrict__ dstW, u16* __restrict__ dstU,
    float* __restrict__ scores, float* __restrict__ sb) {
  __shared__ float red[4][8];
  __shared__ float red2[4];
  int tid = threadIdx.x;
  if (blockIdx.x < 2048) {
    int p = blockIdx.x & 255;
    int es = blockIdx.x >> 8;                    // e-slice 0..7
    int t4 = tid & 63, eg = tid >> 6;            // t = t4*4..+3, e-subgroup eg
    f32x4 wkq[4];
    const f32x4* wkp = (const f32x4*)(WK + es * 64 + eg * 16);
#pragma unroll
    for (int i = 0; i < 4; ++i) wkq[i] = wkp[i];
    const f32x4* base = (const f32x4*)WQ + (size_t)(p * 512 + es * 64 + eg * 16) * 64 + t4;
    f32x4 m4 = {0.f, 0.f, 0.f, 0.f};
#pragma unroll
    for (int i = 0; i < 4; ++i) {
#pragma unroll
      for (int e = 0; e < 4; ++e) {
        f32x4 qv = base[(i * 4 + e) * 64];       // 16 independent 16B loads
        m4 += qv * wkq[i][e];
      }
    }
    // all 8 batches at once: ILP across the shuffle chains, single barrier
    float v[8];
    const f32x4* txp = (const f32x4*)txt;
#pragma unroll
    for (int b = 0; b < 8; ++b) {
      f32x4 tx = txp[b * 64 + t4];
      v[b] = m4[0] * tx[0] + m4[1] * tx[1] + m4[2] * tx[2] + m4[3] * tx[3];
    }
#pragma unroll
    for (int off = 32; off; off >>= 1)
#pragma unroll
      for (int b = 0; b < 8; ++b) v[b] += __shfl_down(v[b], off, 64);
    if (t4 == 0)
#pragma unroll
      for (int b = 0; b < 8; ++b) red[eg][b] = v[b];
    __syncthreads();
    if (tid < 8) {
      float sv = red[0][tid] + red[1][tid] + red[2][tid] + red[3][tid];
      atomicAdd(&scores[tid * 256 + p], sv * 0.044194173824159216f);
    }
    if (blockIdx.x == 0) {
      float vv = WV[tid] * Wsw[tid] + WV[tid + 256] * Wsw[tid + 256];
#pragma unroll
      for (int off = 32; off; off >>= 1) vv += __shfl_down(vv, off, 64);
      if (t4 == 0) red2[eg] = vv;
      __syncthreads();
      if (tid == 0) {
        sb[0] = red2[0] + red2[1] + red2[2] + red2[3];
        sb[1] = Wsb[0];
      }
    }
    return;
  }
  // ---- weight swizzle (LDS-free, fragment-major output) ----
  int sbid = blockIdx.x - 2048;                  // 0..1023
  int set = sbid >> 9;
  int chgrp = (sbid >> 4) & 31;
  int chunk = sbid & 15;
  int q = tid & 3, gch = tid >> 2;               // 4 threads per (gate,chrow)
  int gate = gch >> 4, chrow = gch & 15;
  int ch = chgrp * 16 + chrow;
  const float* s;
  if (set == 0) s = gate == 0 ? wi : gate == 1 ? wf : gate == 2 ? wo : wc;
  else          s = gate == 0 ? ui : gate == 1 ? uf : gate == 2 ? uo : uc;
  // this thread's 72 contiguous floats: [cl = q*8 .. q*8+7][k9 0..8]
  const f32x4* src = (const f32x4*)(s + (size_t)(ch * 512 + chunk * 32) * 9) + q * 18;
  f32x4 va[18];
#pragma unroll
  for (int i = 0; i < 18; ++i) va[i] = src[i];
  u16* dst = (set == 0 ? dstW : dstU) + (size_t)(chgrp * 16 + chunk) * 18432
             + (size_t)(gate * 64 + q * 16 + chrow) * 8;
#pragma unroll
  for (int k9 = 0; k9 < 9; ++k9) {
    i32x4 wv;
#pragma unroll
    for (int w = 0; w < 4; ++w) {
      int i0 = (2 * w) * 9 + k9, i1 = (2 * w + 1) * 9 + k9;
      unsigned lo = f2h(va[i0 >> 2][i0 & 3]);
      unsigned hi = f2h(va[i1 >> 2][i1 & 3]);
      wv[w] = (int)(lo | (hi << 16));
    }
    *(i32x4*)(dst + k9 * 2048) = wv;             // wave covers a full 1KB line set
  }
}

// ---------------------------------------------------------------------------
// prep_inputs: coef from scores (softmax over h per (b,w)); AM = coef*x,
// H0 = x, fp16 NHWC [b][p][ch]. (b,p) are block-uniform -> stage the 16
// scores once in LDS instead of 32 scattered loads per thread.
// ---------------------------------------------------------------------------
__global__ void prep_inputs(const float* __restrict__ x, const float* __restrict__ scores,
                            const float* __restrict__ sb,
                            u16* __restrict__ AM, u16* __restrict__ H0) {
  __shared__ float sc[16];
  int idx = blockIdx.x * 256 + threadIdx.x;  // NHWC flat index
  int ch = idx & 511, p = (idx >> 9) & 255, b = idx >> 17;
  int w = p & 15, h = p >> 4;
  if (threadIdx.x < 16) sc[threadIdx.x] = scores[b * 256 + threadIdx.x * 16 + w];
  __syncthreads();
  float s = sb[0], b0 = sb[1];
  float mx = -1e30f;
#pragma unroll
  for (int hh = 0; hh < 16; ++hh) mx = fmaxf(mx, sc[hh]);
  float den = 0.f, my = 0.f;
#pragma unroll
  for (int hh = 0; hh < 16; ++hh) {
    float e = __expf(sc[hh] - mx);
    den += e;
    if (hh == h) my = e;
  }
  float coef = 1.0f + b0 + s * my / den;
  float xv = x[(size_t)(b * 512 + ch) * 256 + p];
  AM[idx] = f2h(coef * xv);
  H0[idx] = f2h(xv);
}

// ---------------------------------------------------------------------------
// Fused 4-gate 3x3 conv, implicit GEMM (fp16 MFMA 16x16x32, fp32 acc).
// Grid 512 = [b 8][nhalf 2][chgrp 32]. M=64 (4 gates x 16 ch), N=128,
// K = 16 chunks x 288. Single-buffered LDS, m97 2-barrier K-loop with
// global_load_lds(16B) staging.
// LDS-conflict fixes this round:
//  - Alds is FRAGMENT-MAJOR [k9][gate][lane 64][8]: ds_read_b128 at lane*16
//    is linear -> 0 bank conflicts (was 8-way at 64B row stride).
//  - Blds channel-group slot XOR-swizzled with x: slot = quad ^ ((xx>>2)&3),
//    pre-applied at the per-lane GLOBAL source of the DMA (global layout of
//    AM/H unchanged), undone at the ds_read -> 2 lanes/bank-group (free).
// ---------------------------------------------------------------------------
template <int MODE>
__launch_bounds__(256, 2)
__global__ void conv4(const u16* __restrict__ inA, const u16* __restrict__ inH,
                      const u16* __restrict__ wW, const u16* __restrict__ wU,
                      const float* __restrict__ bWi, const float* __restrict__ bUi,
                      const float* __restrict__ bWf, const float* __restrict__ bUf,
                      const float* __restrict__ bWo, const float* __restrict__ bUo,
                      const float* __restrict__ bWc, const float* __restrict__ bUc,
                      float* __restrict__ G, const float* __restrict__ c_src,
                      float* __restrict__ c_dst, u16* __restrict__ h_out,
                      float* __restrict__ out) {
  __shared__ __align__(16) u16 Alds[9 * 4 * 64 * 8];  // [k9][gate][lane][8] 36864 B
  __shared__ __align__(16) u16 Blds[10 * 18 * 32];    // [r][xx][slot 4][8]  11520 B
  const int tid = threadIdx.x;
  const int chgrp = blockIdx.x & 31;
  const int nhalf = (blockIdx.x >> 5) & 1;
  const int b = blockIdx.x >> 6;
  const int wave = tid >> 6, lane = tid & 63;
  const int row = lane & 15, quad = lane >> 4;
  const int NCH = (MODE == 0) ? 32 : 16;
  const int gyBase = nhalf * 8 - 1;   // global input row of Blds row 0

  // Zero Blds once (borders persist; DMA overwrites interior rows only).
  {
    i32x4 z = {0, 0, 0, 0};
    i32x4* bz = (i32x4*)Blds;
#pragma unroll
    for (int i = 0; i < 3; ++i) {
      int k = tid + 256 * i;
      if (k < 720) bz[k] = z;
    }
  }
  __syncthreads();  // zeroing must complete before stage(0)'s DMA lands

  const u16* wsrcW = wW + (size_t)chgrp * 294912;
  const u16* wsrcU = wU + (size_t)chgrp * 294912;
  const u16* isrcA = inA + (size_t)b * 131072;
  const u16* isrcH = inH + (size_t)b * 131072;

  auto stage = [&](int k) {
    const u16* gw;
    const u16* gi;
    if (MODE == 0 && k < 16) { gw = wsrcW + k * 18432; gi = isrcA + k * 32; }
    else                     { gw = wsrcU + (k & 15) * 18432; gi = isrcH + (k & 15) * 32; }
    // weights: straight linear copy of the fragment-major 36864 B slice
#pragma unroll
    for (int i = 0; i < 9; ++i)
      gl16(gw + (i * 256 + tid) * 8, &Alds[(i * 256 + wave * 64) * 8]);
    // input rows: Blds row r <- global row gyBase+r; lane covers (xi, slot).
    // Source channel-group XOR-pre-swizzled so the ds_read side can unswizzle.
    int xi = lane >> 2;
    int qsrc = (lane & 3) ^ (((xi + 1) >> 2) & 3);
#pragma unroll
    for (int j = 0; j < 3; ++j) {
      int r = j * 4 + wave;
      int gy = gyBase + r;
      if (r < 10 && gy >= 0 && gy < 16)
        gl16(gi + (size_t)(gy * 16 + xi) * 512 + qsrc * 8,
             &Blds[r * 576 + 32]);
    }
  };

  f32x4 acc[4][2];
#pragma unroll
  for (int m = 0; m < 4; ++m)
#pragma unroll
    for (int n = 0; n < 2; ++n) acc[m][n] = (f32x4){0.f, 0.f, 0.f, 0.f};

  const int ch0 = chgrp * 16 + quad * 4;
  float* gptr = G + (size_t)blockIdx.x * 8192 + wave * 2048 + lane * 4;

  stage(0);
  __syncthreads();  // barrier drains DMA (vmcnt0) -> chunk 0 ready

#pragma unroll 1
  for (int k = 0; k < NCH; ++k) {
#pragma unroll
    for (int kx = 0; kx < 3; ++kx) {
      int xx = row + kx;
      int qs = quad ^ ((xx >> 2) & 3);          // undo the DMA-side XOR
      f16x8 bfr[4];  // input rows wave*2 .. wave*2+3 (shared across ky,n)
#pragma unroll
      for (int jj = 0; jj < 4; ++jj)
        bfr[jj] = *(const f16x8*)(&Blds[(wave * 2 + jj) * 576 + xx * 32 + qs * 8]);
#pragma unroll
      for (int ky = 0; ky < 3; ++ky) {
#pragma unroll
        for (int m = 0; m < 4; ++m) {
          f16x8 af = *(const f16x8*)(&Alds[((ky * 3 + kx) * 4 + m) * 512 + lane * 8]);
#pragma unroll
          for (int n = 0; n < 2; ++n)
            acc[m][n] = __builtin_amdgcn_mfma_f32_16x16x32_f16(af, bfr[n + ky], acc[m][n], 0, 0, 0);
        }
      }
    }
    if constexpr (MODE == 0) {
      if (k == 15) {  // W-half done: add biases, persist G = conv(AM,W)+bW+bU
#pragma unroll
        for (int m = 0; m < 4; ++m) {
          const float* bw = m == 0 ? bWi : m == 1 ? bWf : m == 2 ? bWo : bWc;
          const float* bu = m == 0 ? bUi : m == 1 ? bUf : m == 2 ? bUo : bUc;
          f32x4 bias;
#pragma unroll
          for (int r = 0; r < 4; ++r) bias[r] = bw[ch0 + r] + bu[ch0 + r];
#pragma unroll
          for (int n = 0; n < 2; ++n) {
            acc[m][n] = acc[m][n] + bias;
            *(f32x4*)(gptr + (m * 2 + n) * 256) = acc[m][n];
          }
        }
      }
    }
    if (k + 1 < NCH) {
      __syncthreads();   // all waves done reading LDS for chunk k
      stage(k + 1);
      __syncthreads();   // barrier drains DMA -> chunk k+1 ready
    }
  }

  // ---- epilogue: LSTM update ----
#pragma unroll
  for (int n = 0; n < 2; ++n) {
    const int p = (nhalf * 8 + wave * 2 + n) * 16 + row;
    f32x4 zi = acc[0][n], zf = acc[1][n], zo = acc[2][n], zg = acc[3][n];
    if constexpr (MODE != 0) {
      zi = zi + *(const f32x4*)(gptr + (0 + n) * 256);
      zf = zf + *(const f32x4*)(gptr + (2 + n) * 256);
      zo = zo + *(const f32x4*)(gptr + (4 + n) * 256);
      zg = zg + *(const f32x4*)(gptr + (6 + n) * 256);
    }
    f32x4 cold;
#pragma unroll
    for (int r = 0; r < 4; ++r)
      cold[r] = c_src[(size_t)(b * 512 + ch0 + r) * 256 + p];
    f32x4 cnew, hv;
#pragma unroll
    for (int r = 0; r < 4; ++r) {
      float iv = sigm(zi[r]);
      float fv = sigm(zf[r]);
      float ov = sigm(zo[r]);
      float gv = tanh_(zg[r]);
      float cn = fmaf(gv, iv, fv * cold[r]);
      cnew[r] = cn;
      hv[r] = tanh_(cn) * ov;
    }
    if constexpr (MODE != 2) {
#pragma unroll
      for (int r = 0; r < 4; ++r)
        c_dst[(size_t)(b * 512 + ch0 + r) * 256 + p] = cnew[r];
      us4 hb;
      hb[0] = f2h(hv[0]); hb[1] = f2h(hv[1]);
      hb[2] = f2h(hv[2]); hb[3] = f2h(hv[3]);
      *(us4*)(h_out + (size_t)b * 131072 + (size_t)p * 512 + ch0) = hb;
    } else {
#pragma unroll
      for (int r = 0; r < 4; ++r)
        out[(size_t)(b * 512 + ch0 + r) * 256 + p] = hv[r];
    }
  }
}

extern "C" void kernel_launch(void* const* d_in, const int* in_sizes, int n_in,
                              void* d_out, int out_size, void* d_ws, size_t ws_size,
                              hipStream_t stream) {
  const float* x    = (const float*)d_in[0];
  const float* txt  = (const float*)d_in[1];
  const float* Wi_w = (const float*)d_in[7];
  const float* Wi_b = (const float*)d_in[8];
  const float* Ui_w = (const float*)d_in[9];
  const float* Ui_b = (const float*)d_in[10];
  const float* Wf_w = (const float*)d_in[11];
  const float* Wf_b = (const float*)d_in[12];
  const float* Uf_w = (const float*)d_in[13];
  const float* Uf_b = (const float*)d_in[14];
  const float* Wc_w = (const float*)d_in[15];
  const float* Wc_b = (const float*)d_in[16];
  const float* Uc_w = (const float*)d_in[17];
  const float* Uc_b = (const float*)d_in[18];
  const float* Wo_w = (const float*)d_in[19];
  const float* Wo_b = (const float*)d_in[20];
  const float* Uo_w = (const float*)d_in[21];
  const float* Uo_b = (const float*)d_in[22];
  const float* WQ   = (const float*)d_in[23];
  const float* WK   = (const float*)d_in[24];
  const float* WV   = (const float*)d_in[25];
  const float* Wsw  = (const float*)d_in[26];
  const float* Wsb  = (const float*)d_in[27];
  (void)in_sizes; (void)n_in; (void)ws_size;

  char* ws = (char*)d_ws;
  size_t off = 0;
  auto carve = [&](size_t n) {
    char* p = ws + off;
    off += (n + 255) & ~(size_t)255;
    return p;
  };
  u16* WswzW    = (u16*)carve(18874368);   // 4x512x512x9 fp16, fragment-major
  u16* WswzU    = (u16*)carve(18874368);
  u16* AM       = (u16*)carve(2097152);    // fp16 NHWC
  u16* H0       = (u16*)carve(2097152);
  u16* H1       = (u16*)carve(2097152);
  float* G      = (float*)carve(16777216); // fragment-layout W-conv + biases
  float* C      = (float*)carve(4194304);  // cell state, NCHW f32
  float* scores = (float*)carve(8192);     // [8 b][256 p]
  float* sb     = (float*)carve(256);      // s, b0

  hipMemsetAsync(scores, 0, 8192, stream);  // scores accumulated via atomicAdd

  prep_big<<<3072, 256, 0, stream>>>(WQ, WK, txt, WV, Wsw, Wsb,
                                     Wi_w, Wf_w, Wo_w, Wc_w,
                                     Ui_w, Uf_w, Uo_w, Uc_w,
                                     WswzW, WswzU, scores, sb);
  prep_inputs<<<4096, 256, 0, stream>>>(x, scores, sb, AM, H0);

  // t=0 fused (W on AM + U on H0), then 3 more timesteps ping-ponging h.
  conv4<0><<<512, 256, 0, stream>>>(AM, H0, WswzW, WswzU,
                                    Wi_b, Ui_b, Wf_b, Uf_b, Wo_b, Uo_b, Wc_b, Uc_b,
                                    G, x, C, H1, nullptr);
  conv4<1><<<512, 256, 0, stream>>>(nullptr, H1, nullptr, WswzU,
                                    nullptr, nullptr, nullptr, nullptr,
                                    nullptr, nullptr, nullptr, nullptr,
                                    G, C, C, H0, nullptr);
  conv4<1><<<512, 256, 0, stream>>>(nullptr, H0, nullptr, WswzU,
                                    nullptr, nullptr, nullptr, nullptr,
                                    nullptr, nullptr, nullptr, nullptr,
                                    G, C, C, H1, nullptr);
  conv4<2><<<512, 256, 0, stream>>>(nullptr, H1, nullptr, WswzU,
                                    nullptr, nullptr, nullptr, nullptr,
                                    nullptr, nullptr, nullptr, nullptr,
                                    G, C, nullptr, nullptr, (float*)d_out);
}